// Round 8
// baseline (197.240 us; speedup 1.0000x reference)
//
#include <hip/hip_runtime.h>
#include <hip/hip_bf16.h>

// Problem constants (B,S,D,H = 2,2048,2048,16 ; DPH = 128)
#define BB 2
#define HH 16
#define SS 2048
#define DD 2048
#define DPH_ 128
#define QBLK 128
#define KBLK 64
#define NT (SS / KBLK)   // 32

// LDS strides (bf16 elements)
#define KSTR 136   // K-LDS  [KBLK][KSTR]  (kv-major, dph contiguous)
#define VSTR 72    // Vt-LDS [DPH][VSTR]   (dph-major, kv contiguous)
#define PSTR 72    // P-LDS  per-wave [16][PSTR]

typedef __bf16 bf16x8 __attribute__((ext_vector_type(8)));
typedef unsigned short u16x8 __attribute__((ext_vector_type(8)));
typedef float f32x4 __attribute__((ext_vector_type(4)));   // native vector (nontemporal-ok)

__device__ __forceinline__ unsigned short f2bfbits(float f) {
  unsigned u = __builtin_bit_cast(unsigned, f);
  u += 0x7FFFu + ((u >> 16) & 1u);   // RNE
  return (unsigned short)(u >> 16);
}
__device__ __forceinline__ __bf16 f2bf(float f) {
  unsigned short s = f2bfbits(f);
  return __builtin_bit_cast(__bf16, s);
}
__device__ __forceinline__ void nt_store4(const float4& v, float* p) {
  f32x4 t = {v.x, v.y, v.z, v.w};
  __builtin_nontemporal_store(t, (f32x4*)p);
}

// Slim preprocessor: q fp32 -> qb bf16 (scratch) + mask passthrough.
// (pk/pv copies are folded into the attention kernel's epilogue.)
template <bool PRE>
__global__ __launch_bounds__(256)
void preproc(const float* __restrict__ q, const int* __restrict__ mask,
             __bf16* __restrict__ qb, float* __restrict__ omask) {
  const size_t i = (size_t)blockIdx.x * 256 + threadIdx.x;  // 1,048,576 total
  const size_t e = i * 8;
  if constexpr (PRE) {
    const float4 v0 = *(const float4*)(q + e);
    const float4 v1 = *(const float4*)(q + e + 4);
    u16x8 t;
    t[0] = f2bfbits(v0.x); t[1] = f2bfbits(v0.y);
    t[2] = f2bfbits(v0.z); t[3] = f2bfbits(v0.w);
    t[4] = f2bfbits(v1.x); t[5] = f2bfbits(v1.y);
    t[6] = f2bfbits(v1.z); t[7] = f2bfbits(v1.w);
    *(u16x8*)(qb + e) = t;
  }
  if (i < (size_t)BB * SS) omask[i] = (float)mask[i];
}

// Fused flash attention, 8 waves x 16 Q-rows = 128 Q-rows per block.
// Writes raw scaled scores to dot_prod as a side effect of the online pass;
// epilogue also emits out and the exact-fp32 prev_key/prev_value copies.
template <bool PRE>
__global__ __launch_bounds__(512, 4)
void attn_fused(const __bf16* __restrict__ qb, const float* __restrict__ qf,
                float* __restrict__ out, float* __restrict__ dot,
                float* __restrict__ pk, float* __restrict__ pv) {
  __shared__ __bf16 kls[KBLK * KSTR];      // 17408 B
  __shared__ __bf16 vls[DPH_ * VSTR];      // 18432 B
  __shared__ __bf16 pls[8 * 16 * PSTR];    // 18432 B   total 54272 B

  // XCD-bijective swizzle: all 16 qt-blocks of one (b,h) land on one XCD.
  const int bid = blockIdx.x;
  const int xcd = bid & 7;
  const int t_  = bid >> 3;          // 0..63
  const int qt  = t_ & 15;
  const int G   = (t_ >> 4) * 8 + xcd;
  const int h   = G & 15;
  const int b   = G >> 4;

  const int tid  = threadIdx.x;
  const int wid  = tid >> 6;
  const int lane = tid & 63;
  const int g    = lane >> 4;   // 0..3
  const int c    = lane & 15;   // 0..15
  const int skv  = lane;        // staging kv row (== tid & 63)

  const int qbase = qt * QBLK;
  const float scale = 0.08838834764831845f;  // 1/sqrt(128)

  const size_t headoff = (size_t)b * SS * DD + (size_t)h * DPH_;
  const __bf16* qbh = PRE ? qb + headoff : nullptr;
  const float*  qfh = qf + headoff;

  // Q fragments: A-layout row = c (within wave's 16 rows), k = st*32+8g+i.
  bf16x8 aq[4];
  {
    const int row = qbase + wid * 16 + c;
    if constexpr (PRE) {
      const __bf16* p = qbh + (size_t)row * DD + 8 * g;
      #pragma unroll
      for (int st = 0; st < 4; ++st) aq[st] = *(const bf16x8*)(p + st * 32);
    } else {
      const float* p = qfh + (size_t)row * DD + 8 * g;
      #pragma unroll
      for (int st = 0; st < 4; ++st) {
        u16x8 t;
        #pragma unroll
        for (int i2 = 0; i2 < 8; ++i2) t[i2] = f2bfbits(p[st * 32 + i2]);
        aq[st] = __builtin_bit_cast(bf16x8, t);
      }
    }
  }

  // Tile staging: each thread owns row skv, octets wid and wid+8 (16B each).
  // Same registers feed both the kv-major K tile and the transposed V tile.
  auto load_tile = [&](int kvb, bf16x8& a0, bf16x8& a1) {
    if constexpr (PRE) {
      const __bf16* p = qbh + (size_t)(kvb + skv) * DD + wid * 8;
      a0 = *(const bf16x8*)p;
      a1 = *(const bf16x8*)(p + 64);
    } else {
      const float* p = qfh + (size_t)(kvb + skv) * DD + wid * 8;
      const float4 f0 = *(const float4*)p;
      const float4 f1 = *(const float4*)(p + 4);
      const float4 f2 = *(const float4*)(p + 64);
      const float4 f3 = *(const float4*)(p + 68);
      u16x8 t0, t1;
      t0[0] = f2bfbits(f0.x); t0[1] = f2bfbits(f0.y);
      t0[2] = f2bfbits(f0.z); t0[3] = f2bfbits(f0.w);
      t0[4] = f2bfbits(f1.x); t0[5] = f2bfbits(f1.y);
      t0[6] = f2bfbits(f1.z); t0[7] = f2bfbits(f1.w);
      t1[0] = f2bfbits(f2.x); t1[1] = f2bfbits(f2.y);
      t1[2] = f2bfbits(f2.z); t1[3] = f2bfbits(f2.w);
      t1[4] = f2bfbits(f3.x); t1[5] = f2bfbits(f3.y);
      t1[6] = f2bfbits(f3.z); t1[7] = f2bfbits(f3.w);
      a0 = __builtin_bit_cast(bf16x8, t0);
      a1 = __builtin_bit_cast(bf16x8, t1);
    }
  };
  auto write_tile = [&](bf16x8 a0, bf16x8 a1) {
    *(bf16x8*)(&kls[skv * KSTR + wid * 8]) = a0;
    *(bf16x8*)(&kls[skv * KSTR + (wid + 8) * 8]) = a1;
    #pragma unroll
    for (int j = 0; j < 8; ++j) {
      vls[(wid * 8 + j) * VSTR + skv] = a0[j];       // contiguous across lanes
      vls[((wid + 8) * 8 + j) * VSTR + skv] = a1[j];
    }
  };

  const f32x4 zero4 = {0.f, 0.f, 0.f, 0.f};
  f32x4 o[8];
  #pragma unroll
  for (int t = 0; t < 8; ++t) o[t] = zero4;
  float m[4], l[4];
  #pragma unroll
  for (int r = 0; r < 4; ++r) { m[r] = -1e30f; l[r] = 0.0f; }

  float* __restrict__ dotb = dot + ((size_t)(b * HH + h) << 22);  // S*S = 2^22

  // Prologue: stage tile 0
  bf16x8 p0, p1;
  load_tile(0, p0, p1);
  write_tile(p0, p1);
  __syncthreads();

  for (int kt = 0; kt < NT; ++kt) {
    const int kvbase = kt * KBLK;

    // ---- QK^T: 16 MFMA; s[ct] holds rows 4g+r, cols ct*16+c ----
    f32x4 s[4];
    #pragma unroll
    for (int ct = 0; ct < 4; ++ct) s[ct] = zero4;
    __builtin_amdgcn_s_setprio(1);
    #pragma unroll
    for (int st = 0; st < 4; ++st) {
      #pragma unroll
      for (int ct = 0; ct < 4; ++ct) {
        bf16x8 bk = *(const bf16x8*)(&kls[(ct * 16 + c) * KSTR + st * 32 + 8 * g]);
        s[ct] = __builtin_amdgcn_mfma_f32_16x16x32_bf16(aq[st], bk, s[ct], 0, 0, 0);
      }
    }
    __builtin_amdgcn_s_setprio(0);

    // ---- T14: issue next tile's global loads; they complete under
    //      softmax + PV and get written to LDS after the barrier ----
    if (kt + 1 < NT) load_tile(kvbase + KBLK, p0, p1);

    // ---- scale + write raw scores to dot_prod (nontemporal: write-once) ----
    #pragma unroll
    for (int ct = 0; ct < 4; ++ct) s[ct] *= scale;
    #pragma unroll
    for (int r = 0; r < 4; ++r) {
      float* dp = dotb + (size_t)(qbase + wid * 16 + 4 * g + r) * SS + kvbase + c;
      #pragma unroll
      for (int ct = 0; ct < 4; ++ct)
        __builtin_nontemporal_store(s[ct][r], dp + ct * 16);
    }

    // ---- online softmax (row reduce across 16 lanes sharing g) ----
    float alpha[4];
    #pragma unroll
    for (int r = 0; r < 4; ++r) {
      float tm = fmaxf(fmaxf(s[0][r], s[1][r]), fmaxf(s[2][r], s[3][r]));
      #pragma unroll
      for (int off = 1; off < 16; off <<= 1) tm = fmaxf(tm, __shfl_xor(tm, off));
      float mn = fmaxf(m[r], tm);
      alpha[r] = __expf(m[r] - mn);
      m[r] = mn;
    }
    float rs[4] = {0.f, 0.f, 0.f, 0.f};
    #pragma unroll
    for (int ct = 0; ct < 4; ++ct) {
      #pragma unroll
      for (int r = 0; r < 4; ++r) {
        float p = __expf(s[ct][r] - m[r]);
        s[ct][r] = p;
        rs[r] += p;
      }
    }
    #pragma unroll
    for (int r = 0; r < 4; ++r) {
      #pragma unroll
      for (int off = 1; off < 16; off <<= 1) rs[r] += __shfl_xor(rs[r], off);
      l[r] = l[r] * alpha[r] + rs[r];
      #pragma unroll
      for (int t = 0; t < 8; ++t) o[t][r] *= alpha[r];
    }

    // ---- P -> per-wave LDS (private region; same-wave read, no barrier) ----
    {
      __bf16* pw = &pls[wid * 16 * PSTR];
      #pragma unroll
      for (int ct = 0; ct < 4; ++ct)
        #pragma unroll
        for (int r = 0; r < 4; ++r)
          pw[(4 * g + r) * PSTR + ct * 16 + c] = f2bf(s[ct][r]);
    }

    // ---- PV: 16 MFMA, accumulate O[8 dph-tiles] ----
    __builtin_amdgcn_s_setprio(1);
    #pragma unroll
    for (int kk = 0; kk < 2; ++kk) {
      bf16x8 ap = *(const bf16x8*)(&pls[(wid * 16 + c) * PSTR + kk * 32 + 8 * g]);
      #pragma unroll
      for (int t = 0; t < 8; ++t) {
        bf16x8 bv = *(const bf16x8*)(&vls[(t * 16 + c) * VSTR + kk * 32 + 8 * g]);
        o[t] = __builtin_amdgcn_mfma_f32_16x16x32_bf16(ap, bv, o[t], 0, 0, 0);
      }
    }
    __builtin_amdgcn_s_setprio(0);

    __syncthreads();                       // all waves done reading kls/vls
    if (kt + 1 < NT) write_tile(p0, p1);   // stage tile kt+1
    __syncthreads();
  }

  // ---- epilogue: normalize and store out[b][q][h*128+d] ----
  #pragma unroll
  for (int r = 0; r < 4; ++r) {
    float inv = 1.0f / l[r];
    float* op = out + (size_t)(b * SS + qbase + wid * 16 + 4 * g + r) * DD + h * DPH_ + c;
    #pragma unroll
    for (int t = 0; t < 8; ++t)
      __builtin_nontemporal_store(o[t][r] * inv, op + t * 16);
  }

  // ---- epilogue: exact-fp32 prev_key/prev_value for this block's rows ----
  // Block (qt,h,b) owns q-rows [qbase, qbase+QBLK) of head h; pk/pv layout
  // [B,H,S,DPH]. 32 lanes x float4 = one 512B row per lane-group.
  {
    const size_t bh = (size_t)b * HH + h;
    const int col = (tid & 31) * 4;
    #pragma unroll
    for (int rr = 0; rr < QBLK; rr += 16) {
      const int row = qbase + rr + (tid >> 5);
      const float4 v = *(const float4*)(qfh + (size_t)row * DD + col);
      nt_store4(v, pk + (bh * SS + row) * DPH_ + col);
      nt_store4(v, pv + (bh * SS + row) * DPH_ + col);
    }
  }
}

extern "C" void kernel_launch(void* const* d_in, const int* in_sizes, int n_in,
                              void* d_out, int out_size, void* d_ws, size_t ws_size,
                              hipStream_t stream) {
  const float* q    = (const float*)d_in[0];
  const int*   mask = (const int*)d_in[1];
  float* out = (float*)d_out;

  // Output layout (concatenated flat, fp32):
  float* o_out  = out;                 // [B,S,D]        8,388,608
  float* o_pk   = out + 8388608;       // [B,H,S,DPH]    8,388,608
  float* o_pv   = out + 16777216;      // [B,H,S,DPH]    8,388,608
  float* o_mask = out + 25165824;      // [B,S]              4,096
  float* o_dot  = out + 25169920;      // [B*H,S,S]    134,217,728

  const size_t need = (size_t)BB * SS * DD * sizeof(__bf16);  // 16.8 MB
  const dim3 agrid(512);  // flat, XCD-swizzled in-kernel (16 qt x 16 h x 2 b)

  if (ws_size >= need) {
    __bf16* qbf = (__bf16*)d_ws;
    preproc<true><<<4096, 256, 0, stream>>>(q, mask, qbf, o_mask);
    attn_fused<true><<<agrid, 512, 0, stream>>>(qbf, q, o_out, o_dot, o_pk, o_pv);
  } else {
    preproc<false><<<4096, 256, 0, stream>>>(q, mask, nullptr, o_mask);
    attn_fused<false><<<agrid, 512, 0, stream>>>(nullptr, q, o_out, o_dot, o_pk, o_pv);
  }
}

// Round 9
// 185.821 us; speedup vs baseline: 1.0615x; 1.0615x over previous
//
#include <hip/hip_runtime.h>
#include <hip/hip_bf16.h>

// Problem constants (B,S,D,H = 2,2048,2048,16 ; DPH = 128)
#define BB 2
#define HH 16
#define SS 2048
#define DD 2048
#define DPH_ 128
#define QBLK 128
#define KBLK 64
#define NT (SS / KBLK)   // 32

// LDS strides (bf16 elements)
#define KSTR 136   // K-LDS  [KBLK][KSTR]  (kv-major, dph contiguous)
#define VSTR 72    // Vt-LDS [DPH][VSTR]   (dph-major, kv contiguous)
#define PSTR 72    // P-LDS  per-wave [32][PSTR]

typedef __bf16 bf16x8 __attribute__((ext_vector_type(8)));
typedef unsigned short u16x8 __attribute__((ext_vector_type(8)));
typedef float f32x4 __attribute__((ext_vector_type(4)));
typedef unsigned int u32x4 __attribute__((ext_vector_type(4)));

__device__ __forceinline__ unsigned f2bfbits32(float f) {
  unsigned u = __builtin_bit_cast(unsigned, f);
  u += 0x7FFFu + ((u >> 16) & 1u);   // RNE
  return u >> 16;
}
__device__ __forceinline__ unsigned short f2bfbits(float f) {
  return (unsigned short)f2bfbits32(f);
}
__device__ __forceinline__ __bf16 f2bf(float f) {
  unsigned short s = f2bfbits(f);
  return __builtin_bit_cast(__bf16, s);
}
__device__ __forceinline__ void nt_store4(const float4& v, float* p) {
  f32x4 t = {v.x, v.y, v.z, v.w};
  __builtin_nontemporal_store(t, (f32x4*)p);
}

// Slim preprocessor: q fp32 -> qb bf16 (scratch) + mask passthrough.
template <bool PRE>
__global__ __launch_bounds__(256)
void preproc(const float* __restrict__ q, const int* __restrict__ mask,
             __bf16* __restrict__ qb, float* __restrict__ omask) {
  const size_t i = (size_t)blockIdx.x * 256 + threadIdx.x;  // 1,048,576 total
  const size_t e = i * 8;
  if constexpr (PRE) {
    const float4 v0 = *(const float4*)(q + e);
    const float4 v1 = *(const float4*)(q + e + 4);
    u16x8 t;
    t[0] = f2bfbits(v0.x); t[1] = f2bfbits(v0.y);
    t[2] = f2bfbits(v0.z); t[3] = f2bfbits(v0.w);
    t[4] = f2bfbits(v1.x); t[5] = f2bfbits(v1.y);
    t[6] = f2bfbits(v1.z); t[7] = f2bfbits(v1.w);
    *(u16x8*)(qb + e) = t;
  }
  if (i < (size_t)BB * SS) omask[i] = (float)mask[i];
}

// Fused flash attention, 4 waves x 32 Q-rows = 128 Q-rows per block.
// Each LDS B-fragment read feeds 2 MFMAs (u in {0,1}) -> half the LDS
// read duplication of the 8-wave variant (the round-8 bottleneck).
template <bool PRE>
__global__ __launch_bounds__(256, 2)
void attn_fused(const __bf16* __restrict__ qb, const float* __restrict__ qf,
                float* __restrict__ out, float* __restrict__ dot,
                float* __restrict__ pk, float* __restrict__ pv) {
  __shared__ __bf16 kls[KBLK * KSTR];      // 17408 B
  __shared__ __bf16 vls[DPH_ * VSTR];      // 18432 B
  __shared__ __bf16 pls[4 * 32 * PSTR];    // 18432 B   total 54272 B

  // XCD-bijective swizzle: all 16 qt-blocks of one (b,h) land on one XCD.
  const int bid = blockIdx.x;
  const int xcd = bid & 7;
  const int t_  = bid >> 3;          // 0..63
  const int qt  = t_ & 15;
  const int G   = (t_ >> 4) * 8 + xcd;
  const int h   = G & 15;
  const int b   = G >> 4;

  const int tid  = threadIdx.x;
  const int wid  = tid >> 6;    // 0..3
  const int lane = tid & 63;
  const int g    = lane >> 4;   // 0..3
  const int c    = lane & 15;   // 0..15

  const int qbase = qt * QBLK;
  const float scale = 0.08838834764831845f;  // 1/sqrt(128)

  const size_t headoff = (size_t)b * SS * DD + (size_t)h * DPH_;
  const __bf16* qbh = PRE ? qb + headoff : nullptr;
  const float*  qfh = qf + headoff;

  // Q fragments: wave's 32 rows = 2 subtiles u; A-layout row=c, k=st*32+8g+i.
  bf16x8 aq[2][4];
  #pragma unroll
  for (int u = 0; u < 2; ++u) {
    const int row = qbase + wid * 32 + u * 16 + c;
    if constexpr (PRE) {
      const __bf16* p = qbh + (size_t)row * DD + 8 * g;
      #pragma unroll
      for (int st = 0; st < 4; ++st) aq[u][st] = *(const bf16x8*)(p + st * 32);
    } else {
      const float* p = qfh + (size_t)row * DD + 8 * g;
      #pragma unroll
      for (int st = 0; st < 4; ++st) {
        u16x8 t;
        #pragma unroll
        for (int i2 = 0; i2 < 8; ++i2) t[i2] = f2bfbits(p[st * 32 + i2]);
        aq[u][st] = __builtin_bit_cast(bf16x8, t);
      }
    }
  }

  // ---- staging ownership (round-4 pairing): thread owns kv rows r0,r0+1,
  //      dph chunk [16*oo, 16*oo+16). 256 threads cover 64x128 tile. ----
  const int p2 = tid & 31;
  const int oo = tid >> 5;           // 0..7
  const int r0 = 2 * p2;

  bf16x8 st0, st1, st2, st3;         // staged bf16: (r0: st0,st1) (r0+1: st2,st3)
  auto load_tile = [&](int kvb) {
    if constexpr (PRE) {
      const __bf16* pA = qbh + (size_t)(kvb + r0) * DD + 16 * oo;
      st0 = *(const bf16x8*)pA;
      st1 = *(const bf16x8*)(pA + 8);
      st2 = *(const bf16x8*)(pA + DD);
      st3 = *(const bf16x8*)(pA + DD + 8);
    } else {
      const float* pA = qfh + (size_t)(kvb + r0) * DD + 16 * oo;
      u16x8 t0, t1, t2, t3;
      #pragma unroll
      for (int i2 = 0; i2 < 8; ++i2) {
        t0[i2] = f2bfbits(pA[i2]);
        t1[i2] = f2bfbits(pA[8 + i2]);
        t2[i2] = f2bfbits(pA[DD + i2]);
        t3[i2] = f2bfbits(pA[DD + 8 + i2]);
      }
      st0 = __builtin_bit_cast(bf16x8, t0);
      st1 = __builtin_bit_cast(bf16x8, t1);
      st2 = __builtin_bit_cast(bf16x8, t2);
      st3 = __builtin_bit_cast(bf16x8, t3);
    }
  };
  auto write_tile = [&]() {
    *(bf16x8*)(&kls[r0 * KSTR + 16 * oo])       = st0;
    *(bf16x8*)(&kls[r0 * KSTR + 16 * oo + 8])   = st1;
    *(bf16x8*)(&kls[(r0+1) * KSTR + 16 * oo])     = st2;
    *(bf16x8*)(&kls[(r0+1) * KSTR + 16 * oo + 8]) = st3;
    // V^T: b32 writes packing the kv row-pair; conflict-free across lanes
    const unsigned* a0 = (const unsigned*)&st0;  // rows r0   elems 2j,2j+1
    const unsigned* a1 = (const unsigned*)&st1;
    const unsigned* b0 = (const unsigned*)&st2;  // rows r0+1
    const unsigned* b1 = (const unsigned*)&st3;
    #pragma unroll
    for (int j = 0; j < 8; ++j) {
      unsigned loA = (j < 4 ? a0[j] : a1[j - 4]);
      unsigned loB = (j < 4 ? b0[j] : b1[j - 4]);
      unsigned w0 = (loA & 0xFFFFu) | (loB << 16);           // elem 2j
      unsigned w1 = (loA >> 16) | (loB & 0xFFFF0000u);       // elem 2j+1
      *(unsigned*)(&vls[(16 * oo + 2 * j) * VSTR + r0]) = w0;
      *(unsigned*)(&vls[(16 * oo + 2 * j + 1) * VSTR + r0]) = w1;
    }
  };

  const f32x4 zero4 = {0.f, 0.f, 0.f, 0.f};
  f32x4 o[2][8];
  #pragma unroll
  for (int u = 0; u < 2; ++u)
    #pragma unroll
    for (int t = 0; t < 8; ++t) o[u][t] = zero4;
  float m[2][4], l[2][4];
  #pragma unroll
  for (int u = 0; u < 2; ++u)
    #pragma unroll
    for (int r = 0; r < 4; ++r) { m[u][r] = -1e30f; l[u][r] = 0.0f; }

  float* __restrict__ dotb = dot + ((size_t)(b * HH + h) << 22);  // S*S = 2^22

  // Prologue: stage tile 0
  load_tile(0);
  write_tile();
  __syncthreads();

  for (int kt = 0; kt < NT; ++kt) {
    const int kvbase = kt * KBLK;

    // ---- QK^T: 16 B-frag reads, 32 MFMA (each bk feeds both u) ----
    f32x4 s[2][4];
    #pragma unroll
    for (int u = 0; u < 2; ++u)
      #pragma unroll
      for (int ct = 0; ct < 4; ++ct) s[u][ct] = zero4;
    __builtin_amdgcn_s_setprio(1);
    #pragma unroll
    for (int st = 0; st < 4; ++st) {
      #pragma unroll
      for (int ct = 0; ct < 4; ++ct) {
        bf16x8 bk = *(const bf16x8*)(&kls[(ct * 16 + c) * KSTR + st * 32 + 8 * g]);
        #pragma unroll
        for (int u = 0; u < 2; ++u)
          s[u][ct] = __builtin_amdgcn_mfma_f32_16x16x32_bf16(aq[u][st], bk, s[u][ct], 0, 0, 0);
      }
    }
    __builtin_amdgcn_s_setprio(0);

    // ---- T14: issue next tile's global loads (complete under softmax+PV) --
    if (kt + 1 < NT) load_tile(kvbase + KBLK);

    // ---- scale + raw scores -> dot_prod (nontemporal) ----
    #pragma unroll
    for (int u = 0; u < 2; ++u) {
      #pragma unroll
      for (int ct = 0; ct < 4; ++ct) s[u][ct] *= scale;
      #pragma unroll
      for (int r = 0; r < 4; ++r) {
        float* dp = dotb + (size_t)(qbase + wid * 32 + u * 16 + 4 * g + r) * SS + kvbase + c;
        #pragma unroll
        for (int ct = 0; ct < 4; ++ct)
          __builtin_nontemporal_store(s[u][ct][r], dp + ct * 16);
      }
    }

    // ---- online softmax per u (row reduce across 16 lanes sharing g) ----
    #pragma unroll
    for (int u = 0; u < 2; ++u) {
      float alpha[4];
      #pragma unroll
      for (int r = 0; r < 4; ++r) {
        float tm = fmaxf(fmaxf(s[u][0][r], s[u][1][r]), fmaxf(s[u][2][r], s[u][3][r]));
        #pragma unroll
        for (int off = 1; off < 16; off <<= 1) tm = fmaxf(tm, __shfl_xor(tm, off));
        float mn = fmaxf(m[u][r], tm);
        alpha[r] = __expf(m[u][r] - mn);
        m[u][r] = mn;
      }
      float rs[4] = {0.f, 0.f, 0.f, 0.f};
      #pragma unroll
      for (int ct = 0; ct < 4; ++ct) {
        #pragma unroll
        for (int r = 0; r < 4; ++r) {
          float p = __expf(s[u][ct][r] - m[u][r]);
          s[u][ct][r] = p;
          rs[r] += p;
        }
      }
      #pragma unroll
      for (int r = 0; r < 4; ++r) {
        #pragma unroll
        for (int off = 1; off < 16; off <<= 1) rs[r] += __shfl_xor(rs[r], off);
        l[u][r] = l[u][r] * alpha[r] + rs[r];
        #pragma unroll
        for (int t = 0; t < 8; ++t) o[u][t][r] *= alpha[r];
      }
      // P -> per-wave LDS region (same-wave read, no barrier needed)
      __bf16* pw = &pls[wid * 32 * PSTR];
      #pragma unroll
      for (int ct = 0; ct < 4; ++ct)
        #pragma unroll
        for (int r = 0; r < 4; ++r)
          pw[(u * 16 + 4 * g + r) * PSTR + ct * 16 + c] = f2bf(s[u][ct][r]);
    }

    // ---- PV: 16 B-frag reads + 4 A reads, 32 MFMA ----
    __builtin_amdgcn_s_setprio(1);
    #pragma unroll
    for (int kk = 0; kk < 2; ++kk) {
      bf16x8 ap[2];
      #pragma unroll
      for (int u = 0; u < 2; ++u)
        ap[u] = *(const bf16x8*)(&pls[wid * 32 * PSTR + (u * 16 + c) * PSTR + kk * 32 + 8 * g]);
      #pragma unroll
      for (int t = 0; t < 8; ++t) {
        bf16x8 bv = *(const bf16x8*)(&vls[(t * 16 + c) * VSTR + kk * 32 + 8 * g]);
        #pragma unroll
        for (int u = 0; u < 2; ++u)
          o[u][t] = __builtin_amdgcn_mfma_f32_16x16x32_bf16(ap[u], bv, o[u][t], 0, 0, 0);
      }
    }
    __builtin_amdgcn_s_setprio(0);

    __syncthreads();                       // all waves done reading kls/vls
    if (kt + 1 < NT) write_tile();         // stage tile kt+1
    __syncthreads();
  }

  // ---- epilogue: normalize and store out[b][q][h*128+d] ----
  #pragma unroll
  for (int u = 0; u < 2; ++u)
    #pragma unroll
    for (int r = 0; r < 4; ++r) {
      float inv = 1.0f / l[u][r];
      float* op = out + (size_t)(b * SS + qbase + wid * 32 + u * 16 + 4 * g + r) * DD + h * DPH_ + c;
      #pragma unroll
      for (int t = 0; t < 8; ++t)
        __builtin_nontemporal_store(o[u][t][r] * inv, op + t * 16);
    }

  // ---- epilogue: exact-fp32 prev_key/prev_value for this block's rows ----
  {
    const size_t bh = (size_t)b * HH + h;
    const int col = (tid & 31) * 4;
    #pragma unroll
    for (int rr = 0; rr < 16; ++rr) {
      const int row = qbase + rr * 8 + (tid >> 5);
      const float4 v = *(const float4*)(qfh + (size_t)row * DD + col);
      nt_store4(v, pk + (bh * SS + row) * DPH_ + col);
      nt_store4(v, pv + (bh * SS + row) * DPH_ + col);
    }
  }
}

extern "C" void kernel_launch(void* const* d_in, const int* in_sizes, int n_in,
                              void* d_out, int out_size, void* d_ws, size_t ws_size,
                              hipStream_t stream) {
  const float* q    = (const float*)d_in[0];
  const int*   mask = (const int*)d_in[1];
  float* out = (float*)d_out;

  // Output layout (concatenated flat, fp32):
  float* o_out  = out;                 // [B,S,D]        8,388,608
  float* o_pk   = out + 8388608;       // [B,H,S,DPH]    8,388,608
  float* o_pv   = out + 16777216;      // [B,H,S,DPH]    8,388,608
  float* o_mask = out + 25165824;      // [B,S]              4,096
  float* o_dot  = out + 25169920;      // [B*H,S,S]    134,217,728

  const size_t need = (size_t)BB * SS * DD * sizeof(__bf16);  // 16.8 MB
  const dim3 agrid(512);  // 16 qt x 16 h x 2 b, XCD-swizzled in-kernel

  if (ws_size >= need) {
    __bf16* qbf = (__bf16*)d_ws;
    preproc<true><<<4096, 256, 0, stream>>>(q, mask, qbf, o_mask);
    attn_fused<true><<<agrid, 256, 0, stream>>>(qbf, q, o_out, o_dot, o_pk, o_pv);
  } else {
    preproc<false><<<4096, 256, 0, stream>>>(q, mask, nullptr, o_mask);
    attn_fused<false><<<agrid, 256, 0, stream>>>(nullptr, q, o_out, o_dot, o_pk, o_pv);
  }
}